// Round 2
// baseline (449.361 us; speedup 1.0000x reference)
//
#include <hip/hip_runtime.h>
#include <math.h>

typedef unsigned short u16;
typedef short short8 __attribute__((ext_vector_type(8)));
typedef short short4v __attribute__((ext_vector_type(4)));
typedef u16 u16x4 __attribute__((ext_vector_type(4)));
typedef float f32x4 __attribute__((ext_vector_type(4)));
typedef __bf16 bf16x8 __attribute__((ext_vector_type(8)));

#define B_ 4
#define T_ 2048
#define D_ 1024
#define H_ 16
#define HD_ 64
#define BT_ 8192  // B_*T_

__device__ __forceinline__ u16 f2bf(float f) {
  unsigned u = __builtin_bit_cast(unsigned, f);
  u = u + 0x7fffu + ((u >> 16) & 1u);  // round-to-nearest-even
  return (u16)(u >> 16);
}
__device__ __forceinline__ f32x4 mfma16(short8 a, short8 b, f32x4 c) {
  return __builtin_amdgcn_mfma_f32_16x16x32_bf16(
      __builtin_bit_cast(bf16x8, a), __builtin_bit_cast(bf16x8, b), c, 0, 0, 0);
}
// async global->LDS, 16B per lane; lds must be wave-uniform-base + lane*16B
__device__ __forceinline__ void async16(u16* lds, const u16* g) {
  __builtin_amdgcn_global_load_lds(
      (const __attribute__((address_space(1))) unsigned int*)g,
      (__attribute__((address_space(3))) unsigned int*)lds, 16, 0, 0);
}

// ---------------------------------------------------------------------------
// f32 -> bf16 elementwise (x conversion). n = 8192*1024, grid 8192 x 256.
// ---------------------------------------------------------------------------
__global__ __launch_bounds__(256) void convert_x(const float* __restrict__ in,
                                                 u16* __restrict__ out) {
  int i = (blockIdx.x * 256 + threadIdx.x) * 4;
  float4 v = *(const float4*)&in[i];
  u16x4 o = {f2bf(v.x), f2bf(v.y), f2bf(v.z), f2bf(v.w)};
  *(u16x4*)&out[i] = o;
}

// ---------------------------------------------------------------------------
// 1024x1024 f32 -> bf16 transpose: Wt[n][k] = bf16(W[k][n])
// ---------------------------------------------------------------------------
__global__ __launch_bounds__(256) void transposeW(const float* __restrict__ in,
                                                  u16* __restrict__ out) {
  __shared__ float sh[32][33];
  const int bx = blockIdx.x * 32, by = blockIdx.y * 32;
  const int col = threadIdx.x & 31, r8 = threadIdx.x >> 5;
#pragma unroll
  for (int i = 0; i < 4; i++) {
    int row = r8 + i * 8;
    sh[row][col] = in[(size_t)(by + row) * 1024 + bx + col];
  }
  __syncthreads();
#pragma unroll
  for (int i = 0; i < 4; i++) {
    int row = r8 + i * 8;
    out[(size_t)(bx + row) * 1024 + by + col] = f2bf(sh[col][row]);
  }
}

// ---------------------------------------------------------------------------
// GEMM, 128x128 tile, BK=32, 4 waves x (64x64 via 4x4 MFMA 16x16x32),
// global_load_lds width-16 staging (m97 recipe).
// vmode==0 (Q/K): Rm=W^T (rows=feature n), Cm=xbf (rows=t). D rows=n ->
//                 4 consecutive hd per lane -> u16x4 store out[bh][t][hd].
// vmode==1 (V):   Rm=xbf (rows=t), Cm=W^T. D rows=t -> u16x4 store
//                 out[bh][hd][t] (V^T).
// ---------------------------------------------------------------------------
__global__ __launch_bounds__(256) void gemm_qkv(const u16* __restrict__ Rm,
                                                const u16* __restrict__ Cm,
                                                const float* __restrict__ bias,
                                                u16* __restrict__ out,
                                                int vmode, float scale) {
  __shared__ __align__(16) u16 Rs[128 * 32];
  __shared__ __align__(16) u16 Cs[128 * 32];
  const int tid = threadIdx.x;
  const int lane = tid & 63;
  const int w = tid >> 6;
  const int wr = w >> 1, wc = w & 1;
  const int c = lane & 15, q4 = lane >> 4;
  const int r0 = blockIdx.y * 128, c0 = blockIdx.x * 128;

  f32x4 acc[4][4];
#pragma unroll
  for (int i = 0; i < 4; i++)
#pragma unroll
    for (int j = 0; j < 4; j++) {
      f32x4 z = {0.f, 0.f, 0.f, 0.f};
      acc[i][j] = z;
    }

  const int rrow = tid >> 2, rch = (tid & 3) * 8;  // LDS offset = tid*8 elems

  for (int kk = 0; kk < 1024; kk += 32) {
    __syncthreads();
    async16(&Rs[tid * 8], &Rm[(size_t)(r0 + rrow) * 1024 + kk + rch]);
    async16(&Rs[2048 + tid * 8], &Rm[(size_t)(r0 + 64 + rrow) * 1024 + kk + rch]);
    async16(&Cs[tid * 8], &Cm[(size_t)(c0 + rrow) * 1024 + kk + rch]);
    async16(&Cs[2048 + tid * 8], &Cm[(size_t)(c0 + 64 + rrow) * 1024 + kk + rch]);
    __syncthreads();
    short8 rF[4], cF[4];
#pragma unroll
    for (int i = 0; i < 4; i++)
      rF[i] = *(const short8*)&Rs[(wr * 64 + i * 16 + c) * 32 + q4 * 8];
#pragma unroll
    for (int j = 0; j < 4; j++)
      cF[j] = *(const short8*)&Cs[(wc * 64 + j * 16 + c) * 32 + q4 * 8];
#pragma unroll
    for (int i = 0; i < 4; i++)
#pragma unroll
      for (int j = 0; j < 4; j++) acc[i][j] = mfma16(rF[i], cF[j], acc[i][j]);
  }

  if (vmode == 0) {
#pragma unroll
    for (int i = 0; i < 4; i++) {
      int ng = r0 + wr * 64 + i * 16 + q4 * 4;  // 4 consecutive features
      int h = ng >> 6, hd = ng & 63;
#pragma unroll
      for (int j = 0; j < 4; j++) {
        int tg = c0 + wc * 64 + j * 16 + c;
        int b = tg >> 11, tt = tg & 2047;
        u16x4 o;
#pragma unroll
        for (int r = 0; r < 4; r++)
          o[r] = f2bf((acc[i][j][r] + bias[ng + r]) * scale);
        *(u16x4*)&out[(((size_t)(b * 16 + h) * 2048 + tt) << 6) + hd] = o;
      }
    }
  } else {
#pragma unroll
    for (int i = 0; i < 4; i++) {
      int tg = r0 + wr * 64 + i * 16 + q4 * 4;  // 4 consecutive t
      int b = tg >> 11, tt = tg & 2047;
#pragma unroll
      for (int j = 0; j < 4; j++) {
        int ng = c0 + wc * 64 + j * 16 + c;
        int h = ng >> 6, hd = ng & 63;
        float bb = bias[ng];
        u16x4 o;
#pragma unroll
        for (int r = 0; r < 4; r++) o[r] = f2bf((acc[i][j][r] + bb) * scale);
        *(u16x4*)&out[((size_t)((b * 16 + h) * 64 + hd)) * 2048 + tt] = o;
      }
    }
  }
}

// ---------------------------------------------------------------------------
// Flash attention. grid (32 qtiles, 64 bh), 4 waves; wave = 16 Q rows.
// 64-key tiles. Qh/Kh: [bh][t][64] bf16 (Q pre-scaled by log2e/8).
// VTh: [bh][64][t] bf16. Softmax in exp2 domain. Output f32.
// ---------------------------------------------------------------------------
__global__ __launch_bounds__(256) void attn_fused(const u16* __restrict__ Qh,
                                                  const u16* __restrict__ Kh,
                                                  const u16* __restrict__ VTh,
                                                  float* __restrict__ out) {
  __shared__ __align__(16) u16 Ks[64 * 64];    // [key][hd]
  __shared__ __align__(16) u16 VTs[64 * 64];   // [hd][key]
  __shared__ __align__(16) u16 Ps[4][16 * 68]; // per-wave P, stride 68
  const int tid = threadIdx.x;
  const int w = tid >> 6, lane = tid & 63;
  const int c = lane & 15, q4 = lane >> 4;
  const int qt = blockIdx.x, bh = blockIdx.y;

  const u16* Qp = Qh + ((size_t)bh * T_ + qt * 64 + w * 16 + c) * 64;
  short8 qf0 = *(const short8*)&Qp[q4 * 8];
  short8 qf1 = *(const short8*)&Qp[32 + q4 * 8];

  const u16* Kb = Kh + (size_t)bh * T_ * 64;
  const u16* Vb = VTh + (size_t)bh * 64 * T_;

  f32x4 O[4];
#pragma unroll
  for (int i = 0; i < 4; i++) {
    f32x4 z = {0.f, 0.f, 0.f, 0.f};
    O[i] = z;
  }
  float mrow[4] = {-INFINITY, -INFINITY, -INFINITY, -INFINITY};
  float lrow[4] = {0.f, 0.f, 0.f, 0.f};

  const int srow = tid >> 3, sch = (tid & 7) * 8;  // LDS offset = tid*8

  for (int kt = 0; kt < T_; kt += 64) {
    __syncthreads();
    async16(&Ks[tid * 8], &Kb[(size_t)(kt + srow) * 64 + sch]);
    async16(&Ks[2048 + tid * 8], &Kb[(size_t)(kt + 32 + srow) * 64 + sch]);
    async16(&VTs[tid * 8], &Vb[(size_t)srow * T_ + kt + sch]);
    async16(&VTs[2048 + tid * 8], &Vb[(size_t)(32 + srow) * T_ + kt + sch]);
    __syncthreads();

    // S = Q K^T (4 blocks of 16 keys); Q carries log2e/8 scale already.
    f32x4 S[4];
#pragma unroll
    for (int kb = 0; kb < 4; kb++) {
      f32x4 z = {0.f, 0.f, 0.f, 0.f};
      S[kb] = z;
      short8 blo = *(const short8*)&Ks[(kb * 16 + c) * 64 + q4 * 8];
      short8 bhi = *(const short8*)&Ks[(kb * 16 + c) * 64 + 32 + q4 * 8];
      S[kb] = mfma16(qf0, blo, S[kb]);
      S[kb] = mfma16(qf1, bhi, S[kb]);
    }

    float mx[4];
#pragma unroll
    for (int r = 0; r < 4; r++)
      mx[r] = fmaxf(fmaxf(S[0][r], S[1][r]), fmaxf(S[2][r], S[3][r]));
#pragma unroll
    for (int d = 1; d < 16; d <<= 1)
#pragma unroll
      for (int r = 0; r < 4; r++) mx[r] = fmaxf(mx[r], __shfl_xor(mx[r], d));

    float al[4], rs[4];
    u16 pb[4][4];
#pragma unroll
    for (int r = 0; r < 4; r++) {
      float mn = fmaxf(mrow[r], mx[r]);
      al[r] = __builtin_amdgcn_exp2f(mrow[r] - mn);
      mrow[r] = mn;
      rs[r] = 0.f;
#pragma unroll
      for (int kb = 0; kb < 4; kb++) {
        float p = __builtin_amdgcn_exp2f(S[kb][r] - mn);
        pb[kb][r] = f2bf(p);
        rs[r] += p;
      }
    }
#pragma unroll
    for (int d = 1; d < 16; d <<= 1)
#pragma unroll
      for (int r = 0; r < 4; r++) rs[r] += __shfl_xor(rs[r], d);
#pragma unroll
    for (int r = 0; r < 4; r++) lrow[r] = lrow[r] * al[r] + rs[r];
#pragma unroll
    for (int i = 0; i < 4; i++)
#pragma unroll
      for (int r = 0; r < 4; r++) O[i][r] *= al[r];

    // P: C-layout -> LDS -> A-layout. Ps is wave-private: no barrier needed,
    // in-wave write->read ordering is enforced by compiler lgkmcnt waits.
    u16* Pw = Ps[w];
#pragma unroll
    for (int r = 0; r < 4; r++)
#pragma unroll
      for (int kb = 0; kb < 4; kb++)
        Pw[(q4 * 4 + r) * 68 + kb * 16 + c] = pb[kb][r];

#pragma unroll
    for (int khf = 0; khf < 2; khf++) {
      short4v plo = *(const short4v*)&Pw[c * 68 + khf * 32 + q4 * 8];
      short4v phi = *(const short4v*)&Pw[c * 68 + khf * 32 + q4 * 8 + 4];
      short8 pf = __builtin_shufflevector(plo, phi, 0, 1, 2, 3, 4, 5, 6, 7);
#pragma unroll
      for (int nb2 = 0; nb2 < 4; nb2++) {
        short8 bv = *(const short8*)&VTs[(nb2 * 16 + c) * 64 + khf * 32 + q4 * 8];
        O[nb2] = mfma16(pf, bv, O[nb2]);
      }
    }
  }

  const int bq = bh >> 4, h = bh & 15;
  float rl[4];
#pragma unroll
  for (int r = 0; r < 4; r++) rl[r] = 1.0f / lrow[r];
#pragma unroll
  for (int nb2 = 0; nb2 < 4; nb2++)
#pragma unroll
    for (int r = 0; r < 4; r++) {
      int t = qt * 64 + w * 16 + q4 * 4 + r;
      out[((size_t)(bq * T_ + t)) * 1024 + h * 64 + nb2 * 16 + c] =
          O[nb2][r] * rl[r];
    }
}

// ---------------------------------------------------------------------------
extern "C" void kernel_launch(void* const* d_in, const int* in_sizes, int n_in,
                              void* d_out, int out_size, void* d_ws, size_t ws_size,
                              hipStream_t stream) {
  (void)in_sizes; (void)n_in; (void)out_size; (void)ws_size;
  const float* x  = (const float*)d_in[0];
  const float* Wq = (const float*)d_in[1];
  const float* bq = (const float*)d_in[2];
  const float* Wk = (const float*)d_in[3];
  const float* bk = (const float*)d_in[4];
  const float* Wv = (const float*)d_in[5];
  const float* bv = (const float*)d_in[6];
  float* out = (float*)d_out;

  // bf16 scratch for x and W^T lives in the front of d_out (32 MB as f32);
  // it is fully consumed before attn_fused overwrites d_out.
  u16* ob  = (u16*)d_out;
  u16* xbf = ob;                              // [8192][1024] bf16 (16 MB)
  u16* wtq = ob + (size_t)BT_ * D_;           // [1024][1024] bf16 (2 MB)
  u16* wtk = wtq + (size_t)D_ * D_;
  u16* wtv = wtk + (size_t)D_ * D_;           // ends at 23 MB < 32 MB

  u16* ws  = (u16*)d_ws;                      // 48 MB of bf16 intermediates
  u16* qh  = ws;                              // [64][2048][64] (Q*log2e/8)
  u16* kh  = qh + (size_t)BT_ * D_;           // [64][2048][64]
  u16* vth = kh + (size_t)BT_ * D_;           // [64][64][2048] (V^T)

  convert_x<<<8192, 256, 0, stream>>>(x, xbf);
  transposeW<<<dim3(32, 32), 256, 0, stream>>>(Wq, wtq);
  transposeW<<<dim3(32, 32), 256, 0, stream>>>(Wk, wtk);
  transposeW<<<dim3(32, 32), 256, 0, stream>>>(Wv, wtv);

  const float qscale = 0.125f * 1.44269504088896f;  // 1/sqrt(64) * log2(e)
  gemm_qkv<<<dim3(64, 8), 256, 0, stream>>>(wtq, xbf, bq, qh, 0, qscale);
  gemm_qkv<<<dim3(64, 8), 256, 0, stream>>>(wtk, xbf, bk, kh, 0, 1.0f);
  gemm_qkv<<<dim3(8, 64), 256, 0, stream>>>(xbf, wtv, bv, vth, 1, 1.0f);

  attn_fused<<<dim3(32, 64), 256, 0, stream>>>(qh, kh, vth, out);
}

// Round 4
// 300.940 us; speedup vs baseline: 1.4932x; 1.4932x over previous
//
#include <hip/hip_runtime.h>
#include <math.h>

typedef unsigned short u16;
typedef short short8 __attribute__((ext_vector_type(8)));
typedef short short4v __attribute__((ext_vector_type(4)));
typedef u16 u16x4 __attribute__((ext_vector_type(4)));
typedef float f32x4 __attribute__((ext_vector_type(4)));
typedef __bf16 bf16x8 __attribute__((ext_vector_type(8)));

#define B_ 4
#define T_ 2048
#define D_ 1024
#define H_ 16
#define HD_ 64
#define BT_ 8192  // B_*T_

__device__ __forceinline__ u16 f2bf(float f) {
  unsigned u = __builtin_bit_cast(unsigned, f);
  u = u + 0x7fffu + ((u >> 16) & 1u);  // round-to-nearest-even
  return (u16)(u >> 16);
}
__device__ __forceinline__ f32x4 mfma16(short8 a, short8 b, f32x4 c) {
  return __builtin_amdgcn_mfma_f32_16x16x32_bf16(
      __builtin_bit_cast(bf16x8, a), __builtin_bit_cast(bf16x8, b), c, 0, 0, 0);
}
// PV MFMA over 16 keys: prefer native 16x16x16; fallback = zero-padded x32
// (A k-slots 4..7 are zero, so B garbage there is multiplied by 0).
#if __has_builtin(__builtin_amdgcn_mfma_f32_16x16x16bf16_1k)
typedef __bf16 bf16x4 __attribute__((ext_vector_type(4)));
__device__ __forceinline__ f32x4 mfma_pv(short4v p, short4v v, f32x4 c) {
  return __builtin_amdgcn_mfma_f32_16x16x16bf16_1k(
      __builtin_bit_cast(bf16x4, p), __builtin_bit_cast(bf16x4, v), c, 0, 0, 0);
}
#else
__device__ __forceinline__ f32x4 mfma_pv(short4v p, short4v v, f32x4 c) {
  short8 a = {p[0], p[1], p[2], p[3], 0, 0, 0, 0};
  short8 b = {v[0], v[1], v[2], v[3], 0, 0, 0, 0};
  return mfma16(a, b, c);
}
#endif
// async global->LDS, 16B/lane; LDS dst must be wave-uniform base + lane*16B
__device__ __forceinline__ void async16(u16* lds, const u16* g) {
  __builtin_amdgcn_global_load_lds(
      (const __attribute__((address_space(1))) unsigned int*)g,
      (__attribute__((address_space(3))) unsigned int*)lds, 16, 0, 0);
}
__device__ __forceinline__ short4v pack4(float p0, float p1, float p2, float p3) {
  u16x4 t = {f2bf(p0), f2bf(p1), f2bf(p2), f2bf(p3)};
  return __builtin_bit_cast(short4v, t);
}

// ---------------------------------------------------------------------------
// f32 -> bf16 elementwise (x conversion). n = 8192*1024, grid 8192 x 256.
// ---------------------------------------------------------------------------
__global__ __launch_bounds__(256) void convert_x(const float* __restrict__ in,
                                                 u16* __restrict__ out) {
  int i = (blockIdx.x * 256 + threadIdx.x) * 4;
  float4 v = *(const float4*)&in[i];
  u16x4 o = {f2bf(v.x), f2bf(v.y), f2bf(v.z), f2bf(v.w)};
  *(u16x4*)&out[i] = o;
}

// ---------------------------------------------------------------------------
// 1024x1024 f32 -> bf16 transpose: Wt[n][k] = bf16(W[k][n])
// ---------------------------------------------------------------------------
__global__ __launch_bounds__(256) void transposeW(const float* __restrict__ in,
                                                  u16* __restrict__ out) {
  __shared__ float sh[32][33];
  const int bx = blockIdx.x * 32, by = blockIdx.y * 32;
  const int col = threadIdx.x & 31, r8 = threadIdx.x >> 5;
#pragma unroll
  for (int i = 0; i < 4; i++) {
    int row = r8 + i * 8;
    sh[row][col] = in[(size_t)(by + row) * 1024 + bx + col];
  }
  __syncthreads();
#pragma unroll
  for (int i = 0; i < 4; i++) {
    int row = r8 + i * 8;
    out[(size_t)(bx + row) * 1024 + by + col] = f2bf(sh[col][row]);
  }
}

// ---------------------------------------------------------------------------
// GEMM, 128x128 tile, BK=64, XOR-swizzled LDS (16B chunk ^= row&7) so the
// MFMA fragment ds_read_b128 is bank-conflict-free. 4 waves x 64x64.
// vmode==0 (Q/K): Rm=W^T, Cm=xbf -> store (XW)^T as out[bh][t][hd] (u16x4).
// vmode==1 (V):   Rm=xbf, Cm=W^T -> store XW as out[bh][hd][t] (V^T).
// ---------------------------------------------------------------------------
__global__ __launch_bounds__(256) void gemm_qkv(const u16* __restrict__ Rm,
                                                const u16* __restrict__ Cm,
                                                const float* __restrict__ bias,
                                                u16* __restrict__ out,
                                                int vmode, float scale) {
  __shared__ __align__(16) u16 Rs[128 * 64];
  __shared__ __align__(16) u16 Cs[128 * 64];
  const int tid = threadIdx.x;
  const int lane = tid & 63;
  const int w = tid >> 6;
  const int wr = w >> 1, wc = w & 1;
  const int c = lane & 15, q4 = lane >> 4;
  const int r0 = blockIdx.y * 128, c0 = blockIdx.x * 128;

  f32x4 acc[4][4];
#pragma unroll
  for (int i = 0; i < 4; i++)
#pragma unroll
    for (int j = 0; j < 4; j++) {
      f32x4 z = {0.f, 0.f, 0.f, 0.f};
      acc[i][j] = z;
    }

  const int sr = tid >> 3, pc = tid & 7;
  const int cx7 = c & 7;

  for (int kk = 0; kk < 1024; kk += 64) {
    __syncthreads();
#pragma unroll
    for (int i = 0; i < 4; i++) {
      int row = i * 32 + sr;
      int sc = (pc ^ (row & 7)) * 8;
      async16(&Rs[(i * 256 + tid) * 8], &Rm[(size_t)(r0 + row) * 1024 + kk + sc]);
      async16(&Cs[(i * 256 + tid) * 8], &Cm[(size_t)(c0 + row) * 1024 + kk + sc]);
    }
    __syncthreads();
#pragma unroll
    for (int h = 0; h < 2; h++) {
      short8 rF[4], cF[4];
#pragma unroll
      for (int i = 0; i < 4; i++)
        rF[i] = *(const short8*)&Rs[(wr * 64 + i * 16 + c) * 64 +
                                    (((h * 4 + q4) ^ cx7) * 8)];
#pragma unroll
      for (int j = 0; j < 4; j++)
        cF[j] = *(const short8*)&Cs[(wc * 64 + j * 16 + c) * 64 +
                                    (((h * 4 + q4) ^ cx7) * 8)];
#pragma unroll
      for (int i = 0; i < 4; i++)
#pragma unroll
        for (int j = 0; j < 4; j++) acc[i][j] = mfma16(rF[i], cF[j], acc[i][j]);
    }
  }

  if (vmode == 0) {
#pragma unroll
    for (int i = 0; i < 4; i++) {
      int ng = r0 + wr * 64 + i * 16 + q4 * 4;  // 4 consecutive features
      int h = ng >> 6, hd = ng & 63;
#pragma unroll
      for (int j = 0; j < 4; j++) {
        int tg = c0 + wc * 64 + j * 16 + c;
        int b = tg >> 11, tt = tg & 2047;
        u16x4 o;
#pragma unroll
        for (int r = 0; r < 4; r++)
          o[r] = f2bf((acc[i][j][r] + bias[ng + r]) * scale);
        *(u16x4*)&out[(((size_t)(b * 16 + h) * 2048 + tt) << 6) + hd] = o;
      }
    }
  } else {
#pragma unroll
    for (int i = 0; i < 4; i++) {
      int tg = r0 + wr * 64 + i * 16 + q4 * 4;  // 4 consecutive t
      int b = tg >> 11, tt = tg & 2047;
#pragma unroll
      for (int j = 0; j < 4; j++) {
        int ng = c0 + wc * 64 + j * 16 + c;
        int h = ng >> 6, hd = ng & 63;
        float bb = bias[ng];
        u16x4 o;
#pragma unroll
        for (int r = 0; r < 4; r++) o[r] = f2bf((acc[i][j][r] + bb) * scale);
        *(u16x4*)&out[((size_t)((b * 16 + h) * 64 + hd)) * 2048 + tt] = o;
      }
    }
  }
}

// ---------------------------------------------------------------------------
// Flash attention v3: S^T formulation. grid (16 qtiles, 64 bh), 4 waves,
// 32 Q rows/wave (2 nblk). K-tile = 64 keys. XOR-swizzled K/V LDS.
// S^T = K.Q^T: C-layout col = Q-row (one lane per row) -> 2-round shuffles,
// and P fragments feed PV (O = P.V) directly as A operands. No P LDS trip.
// Qh/Kh: [bh][t][64] bf16 (Q pre-scaled by log2e/8). VTh: [bh][64][t] bf16.
// ---------------------------------------------------------------------------
__global__ __launch_bounds__(256, 4) void attn_fused(const u16* __restrict__ Qh,
                                                     const u16* __restrict__ Kh,
                                                     const u16* __restrict__ VTh,
                                                     float* __restrict__ out) {
  __shared__ __align__(16) u16 Ks[64 * 64];   // [key][hd], chunk^=key&7
  __shared__ __align__(16) u16 VTs[64 * 64];  // [hd][key], chunk^=hd&7
  const int tid = threadIdx.x;
  const int w = tid >> 6, lane = tid & 63;
  const int c = lane & 15, q4 = lane >> 4;
  const int cx7 = c & 7;
  const int qt = blockIdx.x, bh = blockIdx.y;

  // Q fragments in B-layout: B[n=c][k=q4*8+j] = Q[row][hd]
  short8 qf[2][2];
#pragma unroll
  for (int nblk = 0; nblk < 2; nblk++) {
    const u16* Qp =
        Qh + ((size_t)bh * T_ + qt * 128 + w * 32 + nblk * 16 + c) * 64;
    qf[nblk][0] = *(const short8*)&Qp[q4 * 8];
    qf[nblk][1] = *(const short8*)&Qp[32 + q4 * 8];
  }

  const u16* Kb = Kh + (size_t)bh * T_ * 64;
  const u16* Vb = VTh + (size_t)bh * 64 * T_;

  f32x4 O[2][4];
#pragma unroll
  for (int nblk = 0; nblk < 2; nblk++)
#pragma unroll
    for (int nb = 0; nb < 4; nb++) {
      f32x4 z = {0.f, 0.f, 0.f, 0.f};
      O[nblk][nb] = z;
    }
  float mrow[2] = {-INFINITY, -INFINITY};
  float lrow[2] = {0.f, 0.f};

  const int sr = tid >> 3, pc = tid & 7;

  for (int kt = 0; kt < T_; kt += 64) {
    __syncthreads();
#pragma unroll
    for (int i = 0; i < 2; i++) {
      int r = i * 32 + sr;
      int sc = (pc ^ (r & 7)) * 8;
      async16(&Ks[(i * 256 + tid) * 8], &Kb[(size_t)(kt + r) * 64 + sc]);
      async16(&VTs[(i * 256 + tid) * 8], &Vb[(size_t)r * T_ + kt + sc]);
    }
    __syncthreads();

    // S^T[kb][nblk]: rows = 16 keys of tile kb, cols = 16 Q rows
    f32x4 S[4][2];
#pragma unroll
    for (int kb = 0; kb < 4; kb++) {
      short8 k0 = *(const short8*)&Ks[(kb * 16 + c) * 64 + ((q4 ^ cx7) * 8)];
      short8 k1 =
          *(const short8*)&Ks[(kb * 16 + c) * 64 + (((4 + q4) ^ cx7) * 8)];
#pragma unroll
      for (int nblk = 0; nblk < 2; nblk++) {
        f32x4 z = {0.f, 0.f, 0.f, 0.f};
        S[kb][nblk] = mfma16(k0, qf[nblk][0], z);
        S[kb][nblk] = mfma16(k1, qf[nblk][1], S[kb][nblk]);
      }
    }

    // online softmax; lane owns Q-row c's scores at keys kb*16+q4*4+r
    short4v pf[2][4];
    float alc[2];
#pragma unroll
    for (int nblk = 0; nblk < 2; nblk++) {
      float mx = S[0][nblk][0];
#pragma unroll
      for (int kb = 0; kb < 4; kb++)
#pragma unroll
        for (int r = 0; r < 4; r++) mx = fmaxf(mx, S[kb][nblk][r]);
      mx = fmaxf(mx, __shfl_xor(mx, 16));
      mx = fmaxf(mx, __shfl_xor(mx, 32));
      float mn = fmaxf(mrow[nblk], mx);
      alc[nblk] = __builtin_amdgcn_exp2f(mrow[nblk] - mn);
      mrow[nblk] = mn;
      float rs = 0.f;
#pragma unroll
      for (int kb = 0; kb < 4; kb++) {
        float p0 = __builtin_amdgcn_exp2f(S[kb][nblk][0] - mn);
        float p1 = __builtin_amdgcn_exp2f(S[kb][nblk][1] - mn);
        float p2 = __builtin_amdgcn_exp2f(S[kb][nblk][2] - mn);
        float p3 = __builtin_amdgcn_exp2f(S[kb][nblk][3] - mn);
        rs += (p0 + p1) + (p2 + p3);
        pf[nblk][kb] = pack4(p0, p1, p2, p3);
      }
      rs += __shfl_xor(rs, 16);
      rs += __shfl_xor(rs, 32);
      lrow[nblk] = lrow[nblk] * alc[nblk] + rs;
    }
    // rescale O: O rows are q4*4+r; alc is indexed by row=c -> shfl from lane row
#pragma unroll
    for (int nblk = 0; nblk < 2; nblk++)
#pragma unroll
      for (int r = 0; r < 4; r++) {
        float a = __shfl(alc[nblk], q4 * 4 + r);
#pragma unroll
        for (int nb = 0; nb < 4; nb++) O[nblk][nb][r] *= a;
      }

    // O += P.V  (A = P fragments in-register, B = V^T from LDS)
#pragma unroll
    for (int kb = 0; kb < 4; kb++) {
      int pch = ((kb * 2 + (q4 >> 1)) ^ cx7) * 8 + (q4 & 1) * 4;
#pragma unroll
      for (int nb = 0; nb < 4; nb++) {
        short4v vf = *(const short4v*)&VTs[(nb * 16 + c) * 64 + pch];
        O[0][nb] = mfma_pv(pf[0][kb], vf, O[0][nb]);
        O[1][nb] = mfma_pv(pf[1][kb], vf, O[1][nb]);
      }
    }
  }

  const int bq = bh >> 4, h = bh & 15;
#pragma unroll
  for (int nblk = 0; nblk < 2; nblk++)
#pragma unroll
    for (int r = 0; r < 4; r++) {
      float rl = 1.0f / __shfl(lrow[nblk], q4 * 4 + r);
      int t = qt * 128 + w * 32 + nblk * 16 + q4 * 4 + r;
#pragma unroll
      for (int nb = 0; nb < 4; nb++)
        out[((size_t)(bq * T_ + t)) * 1024 + h * 64 + nb * 16 + c] =
            O[nblk][nb][r] * rl;
    }
}

// ---------------------------------------------------------------------------
extern "C" void kernel_launch(void* const* d_in, const int* in_sizes, int n_in,
                              void* d_out, int out_size, void* d_ws, size_t ws_size,
                              hipStream_t stream) {
  (void)in_sizes; (void)n_in; (void)out_size; (void)ws_size;
  const float* x  = (const float*)d_in[0];
  const float* Wq = (const float*)d_in[1];
  const float* bq = (const float*)d_in[2];
  const float* Wk = (const float*)d_in[3];
  const float* bk = (const float*)d_in[4];
  const float* Wv = (const float*)d_in[5];
  const float* bv = (const float*)d_in[6];
  float* out = (float*)d_out;

  // bf16 scratch for x and W^T lives in the front of d_out (32 MB as f32);
  // fully consumed before attn_fused overwrites d_out.
  u16* ob  = (u16*)d_out;
  u16* xbf = ob;                              // [8192][1024] bf16 (16 MB)
  u16* wtq = ob + (size_t)BT_ * D_;           // [1024][1024] bf16 (2 MB)
  u16* wtk = wtq + (size_t)D_ * D_;
  u16* wtv = wtk + (size_t)D_ * D_;           // ends at 23 MB < 32 MB

  u16* ws  = (u16*)d_ws;                      // 48 MB of bf16 intermediates
  u16* qh  = ws;                              // [64][2048][64] (Q*log2e/8)
  u16* kh  = qh + (size_t)BT_ * D_;           // [64][2048][64]
  u16* vth = kh + (size_t)BT_ * D_;           // [64][64][2048] (V^T)

  convert_x<<<8192, 256, 0, stream>>>(x, xbf);
  transposeW<<<dim3(32, 32), 256, 0, stream>>>(Wq, wtq);
  transposeW<<<dim3(32, 32), 256, 0, stream>>>(Wk, wtk);
  transposeW<<<dim3(32, 32), 256, 0, stream>>>(Wv, wtv);

  const float qscale = 0.125f * 1.44269504088896f;  // 1/sqrt(64) * log2(e)
  gemm_qkv<<<dim3(64, 8), 256, 0, stream>>>(wtq, xbf, bq, qh, 0, qscale);
  gemm_qkv<<<dim3(64, 8), 256, 0, stream>>>(wtk, xbf, bk, kh, 0, 1.0f);
  gemm_qkv<<<dim3(8, 64), 256, 0, stream>>>(xbf, wtv, bv, vth, 1, 1.0f);

  attn_fused<<<dim3(16, 64), 256, 0, stream>>>(qh, kh, vth, out);
}